// Round 5
// baseline (165.186 us; speedup 1.0000x reference)
//
#include <hip/hip_runtime.h>
#include <hip/hip_bf16.h>

#define B_ 16
#define S_ 512
#define H_ 768
#define TS_ 20
#define IS_ 20
#define D_ 808
#define M_ 36
#define E_ 12
#define RNUM_ 97
#define D2_ 50
#define P_ (E_*E_)        // 144
#define NODES_ (M_+1)     // 37
#define NCOL_ (D2_*D_)    // 40400
#define MROWS_ (B_*E_)    // 192
#define KSTEPS_ 26
#define KPAD_ (KSTEPS_*32)  // 832

typedef __attribute__((ext_vector_type(8))) short bf16x8;
typedef __attribute__((ext_vector_type(4))) float f32x4;

__device__ inline unsigned short f2bf(float f) {
  union { float f; unsigned u; } v; v.f = f;
  unsigned r = v.u + 0x7FFFu + ((v.u >> 16) & 1u);
  return (unsigned short)(r >> 16);
}

__device__ inline unsigned pack2bf(float a, float b) {
  union { __hip_bfloat162 h; unsigned u; } p;
  p.h = __float22bfloat162_rn(make_float2(a, b));
  return p.u;
}

// ---------------- kernel 1: mention mean-pooling (+ cls node) ----------------
__global__ __launch_bounds__(256) void k_mention_pool(
    const float* __restrict__ enc_hid, const int* __restrict__ etype,
    const int* __restrict__ eidv, const int* __restrict__ midv,
    const float* __restrict__ type_emb, const float* __restrict__ id_emb,
    float* __restrict__ x) {
  int blk = blockIdx.x;
  int b = blk / NODES_;
  int n = blk % NODES_;
  int t = threadIdx.x;
  float* xrow = x + (size_t)(b * NODES_ + n) * D_;
  if (n == 0) {
    for (int d = t; d < D_; d += 256)
      xrow[d] = (d < H_) ? enc_hid[(size_t)(b * S_) * H_ + d] : 0.0f;
    return;
  }
  float acc[4] = {0.f, 0.f, 0.f, 0.f};
  int cnt = 0;
  for (int s = 0; s < S_; ++s) {
    int m = midv[b * S_ + s];
    if (m != n) continue;
    ++cnt;
    int ty = etype[b * S_ + s];
    int iv = eidv[b * S_ + s];
    #pragma unroll
    for (int ii = 0; ii < 4; ++ii) {
      int d = t + ii * 256;
      if (d < D_) {
        float v;
        if (d < H_) v = enc_hid[(size_t)(b * S_ + s) * H_ + d];
        else if (d < H_ + TS_) v = type_emb[ty * TS_ + (d - H_)];
        else v = id_emb[iv * IS_ + (d - H_ - TS_)];
        acc[ii] += v;
      }
    }
  }
  float inv = (cnt > 0) ? 1.0f / (float)cnt : 0.0f;
  #pragma unroll
  for (int ii = 0; ii < 4; ++ii) {
    int d = t + ii * 256;
    if (d < D_) xrow[d] = acc[ii] * inv;
  }
}

// ---------------- kernel 2: entity pooling + bf16 pre-swizzled A -------------
// ent fp32 [192][808]; eswz bf16 layout [kb=26][g=4][row=192][8] zero-padded.
__global__ __launch_bounds__(256) void k_entity_pool(
    const float* __restrict__ x, const float* __restrict__ tbl,
    float* __restrict__ ent, short* __restrict__ eswz) {
  int blk = blockIdx.x;
  int b = blk / E_;
  int e = blk % E_;
  int t = threadIdx.x;
  const float* trow = tbl + (size_t)(b * (E_ + 1) + (e + 1)) * NODES_;
  __shared__ float w[NODES_];
  __shared__ float sinv;
  if (t < NODES_) w[t] = trow[t];
  __syncthreads();
  if (t == 0) {
    float s = 0.f;
    for (int m = 0; m < NODES_; ++m) s += w[m];
    sinv = (s > 0.f) ? 1.0f / s : 0.0f;
  }
  __syncthreads();
  float inv = sinv;
  for (int d = t; d < D_; d += 256) {
    float a = 0.f;
    for (int m = 0; m < NODES_; ++m)
      a += w[m] * x[(size_t)(b * NODES_ + m) * D_ + d];
    float v = a * inv;
    ent[(size_t)blk * D_ + d] = v;
    int kb = d >> 5, g = (d >> 3) & 3, el = d & 7;
    eswz[((size_t)(kb * 4 + g) * MROWS_ + blk) * 8 + el] = (short)f2bf(v);
  }
  if (t < KPAD_ - D_) {   // zero-pad k = 808..831
    int d = D_ + t;
    int kb = d >> 5, g = (d >> 3) & 3, el = d & 7;
    eswz[((size_t)(kb * 4 + g) * MROWS_ + blk) * 8 + el] = 0;
  }
}

// ---------------- kernel 3: A[192,40400] = Ent @ Wview -----------------------
// BM=192 BN=64 BK=32. NO LDS, NO barriers in K-loop.
// B-frags: direct global fp32 reads of W (L1-hot step-tile), cvt to bf16.
// A-frags: direct global bf16 from pre-swizzled eswz (L2-hot, zero-padded).
// 1-step register prefetch of the 32 B floats.
__global__ __launch_bounds__(256) void k_gemm(
    const float* __restrict__ Wf, const short* __restrict__ eswz,
    float* __restrict__ A) {
  const int tid = threadIdx.x;
  const int lane = tid & 63;
  const int ln15 = lane & 15;
  const int g = (lane >> 4) & 3;
  const int wv = tid >> 6;
  const int colBase = blockIdx.x * 64;

  // per-lane clamped column per nt (clamp only affects masked-out lanes)
  int colc[4];
  #pragma unroll
  for (int nt = 0; nt < 4; ++nt) {
    int c = colBase + nt * 16 + ln15;
    colc[nt] = (c < NCOL_) ? c : (NCOL_ - 1);
  }
  // per-lane W base for this lane's k-group
  const float* wg = Wf + (size_t)(g * 8) * NCOL_;

  f32x4 acc[3][4];
  #pragma unroll
  for (int i = 0; i < 3; ++i)
    #pragma unroll
    for (int j = 0; j < 4; ++j)
      acc[i][j] = (f32x4){0.f, 0.f, 0.f, 0.f};

  float fb[4][8], fn[4][8];

  // LOADB for steps 0..24 (k = t*32 + g*8 + e <= 799 < 808, no clamp needed)
  #define LOADB(tt, dst)                                                      \
    _Pragma("unroll")                                                         \
    for (int nt = 0; nt < 4; ++nt) {                                          \
      _Pragma("unroll")                                                       \
      for (int e = 0; e < 8; ++e)                                             \
        dst[nt][e] = wg[(size_t)((tt) * 32 + e) * NCOL_ + colc[nt]];          \
    }

  LOADB(0, fb);

  for (int t = 0; t < KSTEPS_ - 1; ++t) {
    // prefetch next step's B floats (t+1 <= 24 in-range; t+1==25 handled below)
    if (t + 1 < KSTEPS_ - 1) {
      LOADB(t + 1, fn);
    } else {
      // t+1 == 25: k = 800 + g*8 + e, clamp to 807 (A-side zero-pad kills it)
      #pragma unroll
      for (int nt = 0; nt < 4; ++nt)
        #pragma unroll
        for (int e = 0; e < 8; ++e) {
          int k = 25 * 32 + g * 8 + e;
          if (k > D_ - 1) k = D_ - 1;
          fn[nt][e] = Wf[(size_t)k * NCOL_ + colc[nt]];
        }
    }
    // A fragments (bf16, pre-swizzled, L2-resident)
    bf16x8 af[3];
    const short* ab = eswz + ((size_t)(t * 4 + g) * MROWS_ + wv * 48 + ln15) * 8;
    af[0] = *(const bf16x8*)(ab);
    af[1] = *(const bf16x8*)(ab + 16 * 8);
    af[2] = *(const bf16x8*)(ab + 32 * 8);
    // build B frags from current floats
    bf16x8 bfr[4];
    #pragma unroll
    for (int nt = 0; nt < 4; ++nt) {
      union { bf16x8 v; unsigned u[4]; } u;
      #pragma unroll
      for (int e2 = 0; e2 < 4; ++e2)
        u.u[e2] = pack2bf(fb[nt][2 * e2], fb[nt][2 * e2 + 1]);
      bfr[nt] = u.v;
    }
    #pragma unroll
    for (int mt = 0; mt < 3; ++mt)
      #pragma unroll
      for (int nt = 0; nt < 4; ++nt)
        acc[mt][nt] = __builtin_amdgcn_mfma_f32_16x16x32_bf16(
            af[mt], bfr[nt], acc[mt][nt], 0, 0, 0);
    // rotate prefetch
    #pragma unroll
    for (int nt = 0; nt < 4; ++nt)
      #pragma unroll
      for (int e = 0; e < 8; ++e)
        fb[nt][e] = fn[nt][e];
  }

  {   // last step t = 25
    const int t = KSTEPS_ - 1;
    bf16x8 af[3];
    const short* ab = eswz + ((size_t)(t * 4 + g) * MROWS_ + wv * 48 + ln15) * 8;
    af[0] = *(const bf16x8*)(ab);
    af[1] = *(const bf16x8*)(ab + 16 * 8);
    af[2] = *(const bf16x8*)(ab + 32 * 8);
    bf16x8 bfr[4];
    #pragma unroll
    for (int nt = 0; nt < 4; ++nt) {
      union { bf16x8 v; unsigned u[4]; } u;
      #pragma unroll
      for (int e2 = 0; e2 < 4; ++e2)
        u.u[e2] = pack2bf(fb[nt][2 * e2], fb[nt][2 * e2 + 1]);
      bfr[nt] = u.v;
    }
    #pragma unroll
    for (int mt = 0; mt < 3; ++mt)
      #pragma unroll
      for (int nt = 0; nt < 4; ++nt)
        acc[mt][nt] = __builtin_amdgcn_mfma_f32_16x16x32_bf16(
            af[mt], bfr[nt], acc[mt][nt], 0, 0, 0);
  }
  #undef LOADB

  // epilogue: C/D layout col = lane&15, row = g*4 + j
  #pragma unroll
  for (int mt = 0; mt < 3; ++mt) {
    int row = wv * 48 + mt * 16 + g * 4;
    #pragma unroll
    for (int nt = 0; nt < 4; ++nt) {
      int col = colBase + nt * 16 + ln15;
      if (col < NCOL_) {
        #pragma unroll
        for (int j = 0; j < 4; ++j)
          A[(size_t)(row + j) * NCOL_ + col] = acc[mt][nt][j];
      }
    }
  }
}

// ---------------- kernel 4a: z[blk][r][je] = dot(A-row-slice, ent) ----------
__global__ __launch_bounds__(256) void k_score_z(
    const float* __restrict__ A, const float* __restrict__ ent,
    float* __restrict__ zbuf) {
  int blk = blockIdx.x;         // b*12 + ke
  int rc = blockIdx.y;          // 0..12
  int b = blk / E_;
  int t = threadIdx.x;
  int lane = t & 63;
  int wv = t >> 6;
  __shared__ float entS[E_ * D_];   // 38784 B
  {
    const float4* src = (const float4*)(ent + (size_t)b * E_ * D_);
    float4* dst = (float4*)entS;
    for (int i = t; i < E_ * D_ / 4; i += 256) dst[i] = src[i];
  }
  __syncthreads();
  int r = rc * 4 + wv;
  if (r >= D2_) return;
  const float* arow = A + (size_t)blk * NCOL_ + (size_t)r * D_;
  float p[E_];
  #pragma unroll
  for (int je = 0; je < E_; ++je) p[je] = 0.f;
  for (int j = lane; j < D_; j += 64) {
    float a = arow[j];
    #pragma unroll
    for (int je = 0; je < E_; ++je) p[je] += a * entS[je * D_ + j];
  }
  #pragma unroll
  for (int je = 0; je < E_; ++je)
    #pragma unroll
    for (int off = 32; off > 0; off >>= 1)
      p[je] += __shfl_down(p[je], off, 64);
  if (lane == 0) {
    #pragma unroll
    for (int je = 0; je < E_; ++je)
      zbuf[(size_t)blk * (D2_ * E_) + r * E_ + je] = p[je];
  }
}

// ---------------- kernel 4b: BN + R projection ------------------------------
__global__ __launch_bounds__(256) void k_out(
    const float* __restrict__ zbuf, const float* __restrict__ Rm,
    const float* __restrict__ gam, const float* __restrict__ bet,
    const float* __restrict__ mu, const float* __restrict__ var,
    float* __restrict__ out) {
  int blk = blockIdx.x;   // b*12+ke
  int t = threadIdx.x;
  __shared__ float zS[D2_ * E_];       // 600
  __shared__ float Rs[RNUM_ * D2_];    // 4850
  for (int i = t; i < D2_ * E_; i += 256) {
    int r = i / E_;
    float z = zbuf[(size_t)blk * (D2_ * E_) + i];
    zS[i] = (z - mu[r]) * rsqrtf(var[r] + 1e-5f) * gam[r] + bet[r];
  }
  for (int i = t; i < RNUM_ * D2_; i += 256) Rs[i] = Rm[i];
  __syncthreads();
  for (int o = t; o < E_ * RNUM_; o += 256) {
    int je = o / RNUM_;
    int k = o % RNUM_;
    float s = 0.f;
    #pragma unroll
    for (int r = 0; r < D2_; ++r) s += zS[r * E_ + je] * Rs[k * D2_ + r];
    out[(size_t)blk * (E_ * RNUM_) + o] = s;
  }
}

extern "C" void kernel_launch(void* const* d_in, const int* in_sizes, int n_in,
                              void* d_out, int out_size, void* d_ws, size_t ws_size,
                              hipStream_t stream) {
  const float* enc  = (const float*)d_in[0];
  const int*  etype = (const int*)d_in[1];
  const int*  eidv  = (const int*)d_in[2];
  const int*  midv  = (const int*)d_in[3];
  const float* tbl  = (const float*)d_in[4];
  const float* temb = (const float*)d_in[5];
  const float* iemb = (const float*)d_in[6];
  const float* W    = (const float*)d_in[7];
  const float* Rm   = (const float*)d_in[8];
  const float* gam  = (const float*)d_in[9];
  const float* bet  = (const float*)d_in[10];
  const float* mu   = (const float*)d_in[11];
  const float* var  = (const float*)d_in[12];

  float* ws   = (float*)d_ws;
  float* x    = ws;                                  // 478336 floats
  float* ent  = x + (size_t)B_ * NODES_ * D_;        // +155136
  float* A    = ent + (size_t)MROWS_ * D_;           // +7756800
  float* zbuf = A + (size_t)MROWS_ * NCOL_;          // +115200
  short* eswz = (short*)(zbuf + (size_t)MROWS_ * D2_ * E_);  // 319488 B
  float* out  = (float*)d_out;

  hipLaunchKernelGGL(k_mention_pool, dim3(B_ * NODES_), dim3(256), 0, stream,
                     enc, etype, eidv, midv, temb, iemb, x);
  hipLaunchKernelGGL(k_entity_pool, dim3(MROWS_), dim3(256), 0, stream,
                     x, tbl, ent, eswz);
  hipLaunchKernelGGL(k_gemm, dim3((NCOL_ + 63) / 64), dim3(256), 0, stream,
                     W, eswz, A);
  hipLaunchKernelGGL(k_score_z, dim3(MROWS_, 13), dim3(256), 0, stream,
                     A, ent, zbuf);
  hipLaunchKernelGGL(k_out, dim3(MROWS_), dim3(256), 0, stream,
                     zbuf, Rm, gam, bet, mu, var, out);
}

// Round 6
// 156.711 us; speedup vs baseline: 1.0541x; 1.0541x over previous
//
#include <hip/hip_runtime.h>
#include <hip/hip_bf16.h>

#define B_ 16
#define S_ 512
#define H_ 768
#define TS_ 20
#define IS_ 20
#define D_ 808
#define M_ 36
#define E_ 12
#define RNUM_ 97
#define D2_ 50
#define P_ (E_*E_)        // 144
#define NODES_ (M_+1)     // 37
#define NCOL_ (D2_*D_)    // 40400
#define MROWS_ (B_*E_)    // 192
#define KSTEPS_ 26
#define KPAD_ (KSTEPS_*32)  // 832

typedef __attribute__((ext_vector_type(8))) short bf16x8;
typedef __attribute__((ext_vector_type(4))) float f32x4;

__device__ inline unsigned short f2bf(float f) {
  union { float f; unsigned u; } v; v.f = f;
  unsigned r = v.u + 0x7FFFu + ((v.u >> 16) & 1u);
  return (unsigned short)(r >> 16);
}

__device__ inline unsigned pack2bf(float a, float b) {
  union { __hip_bfloat162 h; unsigned u; } p;
  p.h = __float22bfloat162_rn(make_float2(a, b));
  return p.u;
}

// ---------------- kernel 1: mention mean-pooling (+ cls node) ----------------
__global__ __launch_bounds__(256) void k_mention_pool(
    const float* __restrict__ enc_hid, const int* __restrict__ etype,
    const int* __restrict__ eidv, const int* __restrict__ midv,
    const float* __restrict__ type_emb, const float* __restrict__ id_emb,
    float* __restrict__ x) {
  int blk = blockIdx.x;
  int b = blk / NODES_;
  int n = blk % NODES_;
  int t = threadIdx.x;
  float* xrow = x + (size_t)(b * NODES_ + n) * D_;
  if (n == 0) {
    for (int d = t; d < D_; d += 256)
      xrow[d] = (d < H_) ? enc_hid[(size_t)(b * S_) * H_ + d] : 0.0f;
    return;
  }
  float acc[4] = {0.f, 0.f, 0.f, 0.f};
  int cnt = 0;
  for (int s = 0; s < S_; ++s) {
    int m = midv[b * S_ + s];
    if (m != n) continue;
    ++cnt;
    int ty = etype[b * S_ + s];
    int iv = eidv[b * S_ + s];
    #pragma unroll
    for (int ii = 0; ii < 4; ++ii) {
      int d = t + ii * 256;
      if (d < D_) {
        float v;
        if (d < H_) v = enc_hid[(size_t)(b * S_ + s) * H_ + d];
        else if (d < H_ + TS_) v = type_emb[ty * TS_ + (d - H_)];
        else v = id_emb[iv * IS_ + (d - H_ - TS_)];
        acc[ii] += v;
      }
    }
  }
  float inv = (cnt > 0) ? 1.0f / (float)cnt : 0.0f;
  #pragma unroll
  for (int ii = 0; ii < 4; ++ii) {
    int d = t + ii * 256;
    if (d < D_) xrow[d] = acc[ii] * inv;
  }
}

// ---------------- kernel 2: entity pooling -> bf16 pre-swizzled eswz ---------
// eswz bf16 layout [slice=kb*4+g (26*4)][row=192][8], zero-padded k=808..831.
__global__ __launch_bounds__(256) void k_entity_pool(
    const float* __restrict__ x, const float* __restrict__ tbl,
    short* __restrict__ eswz) {
  int blk = blockIdx.x;
  int b = blk / E_;
  int e = blk % E_;
  int t = threadIdx.x;
  const float* trow = tbl + (size_t)(b * (E_ + 1) + (e + 1)) * NODES_;
  __shared__ float w[NODES_];
  __shared__ float sinv;
  if (t < NODES_) w[t] = trow[t];
  __syncthreads();
  if (t == 0) {
    float s = 0.f;
    for (int m = 0; m < NODES_; ++m) s += w[m];
    sinv = (s > 0.f) ? 1.0f / s : 0.0f;
  }
  __syncthreads();
  float inv = sinv;
  for (int d = t; d < D_; d += 256) {
    float a = 0.f;
    for (int m = 0; m < NODES_; ++m)
      a += w[m] * x[(size_t)(b * NODES_ + m) * D_ + d];
    float v = a * inv;
    int slice = d >> 3;            // (kb*4+g) = d/8
    int el = d & 7;
    eswz[((size_t)slice * MROWS_ + blk) * 8 + el] = (short)f2bf(v);
  }
  if (t < KPAD_ - D_) {   // zero-pad k = 808..831
    int d = D_ + t;
    eswz[((size_t)(d >> 3) * MROWS_ + blk) * 8 + (d & 7)] = 0;
  }
}

// ---------------- kernel 2b: W fp32 -> bf16 fragment-ready layout ------------
// Wbf[slice=kb*4+g][c=40400][e=8] = Wview[kb*32+g*8+e][c]; zero for k>=808.
__global__ __launch_bounds__(256) void k_wconv(
    const float* __restrict__ Wf, short* __restrict__ Wbf) {
  int slice = blockIdx.y;                 // 0..103
  int c = blockIdx.x * 256 + threadIdx.x;
  if (c >= NCOL_) return;
  int k0 = (slice >> 2) * 32 + (slice & 3) * 8;
  float v[8];
  #pragma unroll
  for (int e = 0; e < 8; ++e) {
    int k = k0 + e;
    v[e] = (k < D_) ? Wf[(size_t)k * NCOL_ + c] : 0.0f;
  }
  union { bf16x8 s; unsigned u[4]; } p;
  #pragma unroll
  for (int e2 = 0; e2 < 4; ++e2) p.u[e2] = pack2bf(v[2 * e2], v[2 * e2 + 1]);
  *(bf16x8*)&Wbf[((size_t)slice * NCOL_ + c) * 8] = p.s;
}

// ---------------- kernel 3: Abf[192,40400] = Ent @ Wview (bf16 out) ----------
// BM=192 BN=64. No LDS, no barriers, no conversion in the K-loop:
// A-frags = dwordx4 from eswz (L2-hot), B-frags = dwordx4 from Wbf (streamed).
// 2-step ping-pong prefetch. Output stored as bf16.
__global__ __launch_bounds__(256) void k_gemm(
    const short* __restrict__ Wbf, const short* __restrict__ eswz,
    short* __restrict__ Abf) {
  const int tid = threadIdx.x;
  const int ln15 = tid & 15;
  const int g = (tid >> 4) & 3;
  const int wv = tid >> 6;
  const int colBase = blockIdx.x * 64;

  int col[4]; bool cok[4];
  #pragma unroll
  for (int nt = 0; nt < 4; ++nt) {
    int c = colBase + nt * 16 + ln15;
    cok[nt] = (c < NCOL_);
    col[nt] = cok[nt] ? c : (NCOL_ - 1);
  }

  f32x4 acc[3][4];
  #pragma unroll
  for (int i = 0; i < 3; ++i)
    #pragma unroll
    for (int j = 0; j < 4; ++j)
      acc[i][j] = (f32x4){0.f, 0.f, 0.f, 0.f};

  auto LOADA = [&](int t, bf16x8* af) {
    #pragma unroll
    for (int mt = 0; mt < 3; ++mt)
      af[mt] = *(const bf16x8*)&eswz[
          ((size_t)(t * 4 + g) * MROWS_ + wv * 48 + mt * 16 + ln15) * 8];
  };
  auto LOADB = [&](int t, bf16x8* bf) {
    #pragma unroll
    for (int nt = 0; nt < 4; ++nt)
      bf[nt] = *(const bf16x8*)&Wbf[((size_t)(t * 4 + g) * NCOL_ + col[nt]) * 8];
  };
  auto MM = [&](bf16x8* af, bf16x8* bf) {
    #pragma unroll
    for (int mt = 0; mt < 3; ++mt)
      #pragma unroll
      for (int nt = 0; nt < 4; ++nt)
        acc[mt][nt] = __builtin_amdgcn_mfma_f32_16x16x32_bf16(
            af[mt], bf[nt], acc[mt][nt], 0, 0, 0);
  };

  bf16x8 aA[3], bA[4], aB[3], bB[4];
  LOADA(0, aA); LOADB(0, bA);
  for (int t = 0; t < KSTEPS_; t += 2) {
    LOADA(t + 1, aB); LOADB(t + 1, bB);      // t+1 <= 25 always valid
    MM(aA, bA);
    if (t + 2 < KSTEPS_) { LOADA(t + 2, aA); LOADB(t + 2, bA); }
    MM(aB, bB);
  }

  // epilogue: C/D layout col = lane&15, row = g*4 + j; store bf16
  #pragma unroll
  for (int mt = 0; mt < 3; ++mt) {
    int row = wv * 48 + mt * 16 + g * 4;
    #pragma unroll
    for (int nt = 0; nt < 4; ++nt) {
      if (cok[nt]) {
        #pragma unroll
        for (int j = 0; j < 4; ++j)
          Abf[(size_t)(row + j) * NCOL_ + col[nt]] = (short)f2bf(acc[mt][nt][j]);
      }
    }
  }
}

// ---------------- kernel 4a: z via MFMA — one wave per (b, r) ---------------
// z[b,ke,je,r] = sum_j Abf[(b,ke)][r*808+j] * ent_bf[(b,je)][j]
// A-op rows = ke (Abf slice, 16B frags), B-op cols = je (eswz frags).
// eswz zero-pad makes the k=800..831 tail exact.
__global__ __launch_bounds__(64) void k_score_z(
    const short* __restrict__ Abf, const short* __restrict__ eswz,
    float* __restrict__ zbuf) {
  int w = blockIdx.x;            // 0..799
  int b = w / D2_;
  int r = w % D2_;
  int lane = threadIdx.x;
  int ln15 = lane & 15;
  int g = lane >> 4;
  int m = b * E_ + ln15;
  if (m > MROWS_ - 1) m = MROWS_ - 1;
  const short* ab = Abf + (size_t)m * NCOL_ + (size_t)r * D_ + g * 8;
  const short* bb = eswz + ((size_t)g * MROWS_ + m) * 8;
  f32x4 acc = (f32x4){0.f, 0.f, 0.f, 0.f};
  #pragma unroll
  for (int t = 0; t < KSTEPS_; ++t) {
    bf16x8 af = *(const bf16x8*)(ab + t * 32);
    bf16x8 bf = *(const bf16x8*)(bb + (size_t)t * 4 * MROWS_ * 8);
    acc = __builtin_amdgcn_mfma_f32_16x16x32_bf16(af, bf, acc, 0, 0, 0);
  }
  if (ln15 < E_ && g < 3) {
    #pragma unroll
    for (int jj = 0; jj < 4; ++jj)
      zbuf[(size_t)(b * E_ + g * 4 + jj) * (D2_ * E_) + r * E_ + ln15] = acc[jj];
  }
}

// ---------------- kernel 4b: BN + R projection ------------------------------
__global__ __launch_bounds__(256) void k_out(
    const float* __restrict__ zbuf, const float* __restrict__ Rm,
    const float* __restrict__ gam, const float* __restrict__ bet,
    const float* __restrict__ mu, const float* __restrict__ var,
    float* __restrict__ out) {
  int blk = blockIdx.x;   // b*12+ke
  int t = threadIdx.x;
  __shared__ float zS[D2_ * E_];       // 600
  __shared__ float Rs[RNUM_ * D2_];    // 4850
  for (int i = t; i < D2_ * E_; i += 256) {
    int r = i / E_;
    float z = zbuf[(size_t)blk * (D2_ * E_) + i];
    zS[i] = (z - mu[r]) * rsqrtf(var[r] + 1e-5f) * gam[r] + bet[r];
  }
  for (int i = t; i < RNUM_ * D2_; i += 256) Rs[i] = Rm[i];
  __syncthreads();
  for (int o = t; o < E_ * RNUM_; o += 256) {
    int je = o / RNUM_;
    int k = o % RNUM_;
    float s = 0.f;
    #pragma unroll
    for (int r = 0; r < D2_; ++r) s += zS[r * E_ + je] * Rs[k * D2_ + r];
    out[(size_t)blk * (E_ * RNUM_) + o] = s;
  }
}

extern "C" void kernel_launch(void* const* d_in, const int* in_sizes, int n_in,
                              void* d_out, int out_size, void* d_ws, size_t ws_size,
                              hipStream_t stream) {
  const float* enc  = (const float*)d_in[0];
  const int*  etype = (const int*)d_in[1];
  const int*  eidv  = (const int*)d_in[2];
  const int*  midv  = (const int*)d_in[3];
  const float* tbl  = (const float*)d_in[4];
  const float* temb = (const float*)d_in[5];
  const float* iemb = (const float*)d_in[6];
  const float* W    = (const float*)d_in[7];
  const float* Rm   = (const float*)d_in[8];
  const float* gam  = (const float*)d_in[9];
  const float* bet  = (const float*)d_in[10];
  const float* mu   = (const float*)d_in[11];
  const float* var  = (const float*)d_in[12];

  // ws layout (floats):
  //   zbuf 115200 | eswz 159744 shorts | Abf 7756800 shorts | Wbf 33612800 shorts
  //   x (478336 f) overlays the Wbf region (dead before k_wconv runs)
  float* ws   = (float*)d_ws;
  float* zbuf = ws;                                       // 115,200 f
  short* eswz = (short*)(zbuf + (size_t)MROWS_ * D2_ * E_);   // 159,744 sh
  short* Abf  = eswz + (size_t)104 * MROWS_ * 8;              // 7,756,800 sh
  short* Wbf  = Abf + (size_t)MROWS_ * NCOL_;                 // 33,612,800 sh
  float* x    = (float*)Wbf;                                  // overlay
  float* out  = (float*)d_out;

  hipLaunchKernelGGL(k_mention_pool, dim3(B_ * NODES_), dim3(256), 0, stream,
                     enc, etype, eidv, midv, temb, iemb, x);
  hipLaunchKernelGGL(k_entity_pool, dim3(MROWS_), dim3(256), 0, stream,
                     x, tbl, eswz);
  hipLaunchKernelGGL(k_wconv, dim3((NCOL_ + 255) / 256, 104), dim3(256), 0,
                     stream, W, Wbf);
  hipLaunchKernelGGL(k_gemm, dim3((NCOL_ + 63) / 64), dim3(256), 0, stream,
                     Wbf, eswz, Abf);
  hipLaunchKernelGGL(k_score_z, dim3(B_ * D2_), dim3(64), 0, stream,
                     Abf, eswz, zbuf);
  hipLaunchKernelGGL(k_out, dim3(MROWS_), dim3(256), 0, stream,
                     zbuf, Rm, gam, bet, mu, var, out);
}

// Round 8
// 141.305 us; speedup vs baseline: 1.1690x; 1.1090x over previous
//
#include <hip/hip_runtime.h>
#include <hip/hip_bf16.h>

#define B_ 16
#define S_ 512
#define H_ 768
#define TS_ 20
#define IS_ 20
#define D_ 808
#define M_ 36
#define E_ 12
#define RNUM_ 97
#define D2_ 50
#define P_ (E_*E_)        // 144
#define NODES_ (M_+1)     // 37
#define NCOL_ (D2_*D_)    // 40400
#define MROWS_ (B_*E_)    // 192
#define KSTEPS_ 26
#define KPAD_ (KSTEPS_*32)  // 832
#define BLKPAD_ 1040        // 1024B (4 k-rows x 64 cols fp32) + 16B pad
#define TILEB_ (8*BLKPAD_)  // 8320 B per K-step tile

typedef __attribute__((ext_vector_type(8))) short bf16x8;
typedef __attribute__((ext_vector_type(4))) float f32x4;

__device__ inline unsigned short f2bf(float f) {
  union { float f; unsigned u; } v; v.f = f;
  unsigned r = v.u + 0x7FFFu + ((v.u >> 16) & 1u);
  return (unsigned short)(r >> 16);
}

__device__ inline unsigned pack2bf(float a, float b) {
  union { __hip_bfloat162 h; unsigned u; } p;
  p.h = __float22bfloat162_rn(make_float2(a, b));
  return p.u;
}

__device__ inline void gll16(const float* src, void* lds) {
  __builtin_amdgcn_global_load_lds(
      (const __attribute__((address_space(1))) unsigned int*)src,
      (__attribute__((address_space(3))) unsigned int*)lds, 16, 0, 0);
}

// ---------------- kernel 1: mention mean-pooling (+ cls node) ----------------
__global__ __launch_bounds__(256) void k_mention_pool(
    const float* __restrict__ enc_hid, const int* __restrict__ etype,
    const int* __restrict__ eidv, const int* __restrict__ midv,
    const float* __restrict__ type_emb, const float* __restrict__ id_emb,
    float* __restrict__ x) {
  int blk = blockIdx.x;
  int b = blk / NODES_;
  int n = blk % NODES_;
  int t = threadIdx.x;
  float* xrow = x + (size_t)(b * NODES_ + n) * D_;
  if (n == 0) {
    for (int d = t; d < D_; d += 256)
      xrow[d] = (d < H_) ? enc_hid[(size_t)(b * S_) * H_ + d] : 0.0f;
    return;
  }
  float acc[4] = {0.f, 0.f, 0.f, 0.f};
  int cnt = 0;
  for (int s = 0; s < S_; ++s) {
    int m = midv[b * S_ + s];
    if (m != n) continue;
    ++cnt;
    int ty = etype[b * S_ + s];
    int iv = eidv[b * S_ + s];
    #pragma unroll
    for (int ii = 0; ii < 4; ++ii) {
      int d = t + ii * 256;
      if (d < D_) {
        float v;
        if (d < H_) v = enc_hid[(size_t)(b * S_ + s) * H_ + d];
        else if (d < H_ + TS_) v = type_emb[ty * TS_ + (d - H_)];
        else v = id_emb[iv * IS_ + (d - H_ - TS_)];
        acc[ii] += v;
      }
    }
  }
  float inv = (cnt > 0) ? 1.0f / (float)cnt : 0.0f;
  #pragma unroll
  for (int ii = 0; ii < 4; ++ii) {
    int d = t + ii * 256;
    if (d < D_) xrow[d] = acc[ii] * inv;
  }
}

// ---------------- kernel 2: entity pooling -> bf16 pre-swizzled eswz ---------
// eswz bf16 layout [slice=kb*4+g (26*4)][row=192][8], zero-padded k=808..831.
__global__ __launch_bounds__(256) void k_entity_pool(
    const float* __restrict__ x, const float* __restrict__ tbl,
    short* __restrict__ eswz) {
  int blk = blockIdx.x;
  int b = blk / E_;
  int e = blk % E_;
  int t = threadIdx.x;
  const float* trow = tbl + (size_t)(b * (E_ + 1) + (e + 1)) * NODES_;
  __shared__ float w[NODES_];
  __shared__ float sinv;
  if (t < NODES_) w[t] = trow[t];
  __syncthreads();
  if (t == 0) {
    float s = 0.f;
    for (int m = 0; m < NODES_; ++m) s += w[m];
    sinv = (s > 0.f) ? 1.0f / s : 0.0f;
  }
  __syncthreads();
  float inv = sinv;
  for (int d = t; d < D_; d += 256) {
    float a = 0.f;
    for (int m = 0; m < NODES_; ++m)
      a += w[m] * x[(size_t)(b * NODES_ + m) * D_ + d];
    float v = a * inv;
    int slice = d >> 3;
    int el = d & 7;
    eswz[((size_t)slice * MROWS_ + blk) * 8 + el] = (short)f2bf(v);
  }
  if (t < KPAD_ - D_) {   // zero-pad k = 808..831
    int d = D_ + t;
    eswz[((size_t)(d >> 3) * MROWS_ + blk) * 8 + (d & 7)] = 0;
  }
}

// ---------------- kernel 3: Abf[192,40400] = Ent @ Wview (fused, 1 W pass) ---
// BM=192 BN=64 BK=32. W fp32 -> LDS via global_load_lds, padded layout:
// byte(k,c) = (k>>2)*1040 + (k&3)*256 + c*4  (16B pad per 4-row block ->
// bank = (4*(k>>2)+c)%32 -> exactly 2-way = free).
// Waves 2x2: wave owns 96 rows x 32 cols -> B LDS reads = 16KB/step (2x amp).
// A-frags direct bf16 global from eswz (L2-hot). 3-buf, stage 2 ahead.
__global__ __launch_bounds__(256) void k_gemm(
    const float* __restrict__ Wf, const short* __restrict__ eswz,
    short* __restrict__ Abf) {
  __shared__ __align__(16) char Bs[3 * TILEB_];   // 24.96 KiB
  const int tid = threadIdx.x;
  const int lane = tid & 63;
  const int ln15 = lane & 15;
  const int g = (lane >> 4) & 3;
  const int wv = tid >> 6;
  const int wr = wv >> 1;          // 0..1: row half (96 rows)
  const int wc = wv & 1;           // 0..1: col half (32 cols)
  const int colBase = blockIdx.x * 64;

  f32x4 acc[6][2];
  #pragma unroll
  for (int i = 0; i < 6; ++i)
    #pragma unroll
    for (int j = 0; j < 2; ++j)
      acc[i][j] = (f32x4){0.f, 0.f, 0.f, 0.f};

  // stage tile t into buffer bufi: 2 instrs/thread, each = one 4-row block
  auto STAGE = [&](int t, int bufi) {
    #pragma unroll
    for (int r2 = 0; r2 < 2; ++r2) {
      int bi = r2 * 4 + wv;                      // block 0..7 (wave-uniform)
      int kg = t * 32 + bi * 4 + (lane >> 4);    // per-lane k row
      if (kg > D_ - 1) kg = D_ - 1;              // tail: killed by eswz zeros
      int cg = colBase + ln15 * 4;
      if (cg > NCOL_ - 4) cg = NCOL_ - 4;        // last block clamp
      gll16(Wf + (size_t)kg * NCOL_ + cg, Bs + bufi * TILEB_ + bi * BLKPAD_);
    }
  };

  STAGE(0, 0);
  STAGE(1, 1);
  __syncthreads();

  int rb = 0;
  for (int t = 0; t < KSTEPS_; ++t) {
    int sb = rb + 2; if (sb >= 3) sb -= 3;
    if (t + 2 < KSTEPS_) STAGE(t + 2, sb);
    const char* bb = Bs + rb * TILEB_;
    // B fragments: 16 fp32 LDS reads (2-way banks = free), cvt to bf16
    bf16x8 bfr[2];
    #pragma unroll
    for (int nt = 0; nt < 2; ++nt) {
      float f[8];
      #pragma unroll
      for (int e = 0; e < 8; ++e) {
        int k = g * 8 + e;
        int col = wc * 32 + nt * 16 + ln15;
        f[e] = *(const float*)(bb + (k >> 2) * BLKPAD_ + (k & 3) * 256 + col * 4);
      }
      union { bf16x8 v; unsigned u[4]; } u;
      #pragma unroll
      for (int e2 = 0; e2 < 4; ++e2)
        u.u[e2] = pack2bf(f[2 * e2], f[2 * e2 + 1]);
      bfr[nt] = u.v;
    }
    // A fragments: 6 x dwordx4 from eswz (L2-resident)
    bf16x8 af[6];
    #pragma unroll
    for (int mt = 0; mt < 6; ++mt)
      af[mt] = *(const bf16x8*)&eswz[
          ((size_t)(t * 4 + g) * MROWS_ + wr * 96 + mt * 16 + ln15) * 8];
    #pragma unroll
    for (int mt = 0; mt < 6; ++mt)
      #pragma unroll
      for (int nt = 0; nt < 2; ++nt)
        acc[mt][nt] = __builtin_amdgcn_mfma_f32_16x16x32_bf16(
            af[mt], bfr[nt], acc[mt][nt], 0, 0, 0);
    __syncthreads();
    rb = (rb == 2) ? 0 : rb + 1;
  }

  // epilogue: C/D layout col = lane&15, row = g*4 + j; store bf16
  #pragma unroll
  for (int mt = 0; mt < 6; ++mt) {
    int row = wr * 96 + mt * 16 + g * 4;
    #pragma unroll
    for (int nt = 0; nt < 2; ++nt) {
      int col = colBase + wc * 32 + nt * 16 + ln15;
      if (col < NCOL_) {
        #pragma unroll
        for (int j = 0; j < 4; ++j)
          Abf[(size_t)(row + j) * NCOL_ + col] = (short)f2bf(acc[mt][nt][j]);
      }
    }
  }
}

// ---------------- kernel 4a: z via MFMA — one wave per (b, r) ---------------
__global__ __launch_bounds__(64) void k_score_z(
    const short* __restrict__ Abf, const short* __restrict__ eswz,
    float* __restrict__ zbuf) {
  int w = blockIdx.x;            // 0..799
  int b = w / D2_;
  int r = w % D2_;
  int lane = threadIdx.x;
  int ln15 = lane & 15;
  int g = lane >> 4;
  int m = b * E_ + ln15;
  if (m > MROWS_ - 1) m = MROWS_ - 1;
  const short* ab = Abf + (size_t)m * NCOL_ + (size_t)r * D_ + g * 8;
  const short* bb = eswz + ((size_t)g * MROWS_ + m) * 8;
  f32x4 acc = (f32x4){0.f, 0.f, 0.f, 0.f};
  #pragma unroll
  for (int t = 0; t < KSTEPS_; ++t) {
    bf16x8 af = *(const bf16x8*)(ab + t * 32);
    bf16x8 bf = *(const bf16x8*)(bb + (size_t)t * 4 * MROWS_ * 8);
    acc = __builtin_amdgcn_mfma_f32_16x16x32_bf16(af, bf, acc, 0, 0, 0);
  }
  if (ln15 < E_ && g < 3) {
    #pragma unroll
    for (int jj = 0; jj < 4; ++jj)
      zbuf[(size_t)(b * E_ + g * 4 + jj) * (D2_ * E_) + r * E_ + ln15] = acc[jj];
  }
}

// ---------------- kernel 4b: BN + R projection ------------------------------
__global__ __launch_bounds__(256) void k_out(
    const float* __restrict__ zbuf, const float* __restrict__ Rm,
    const float* __restrict__ gam, const float* __restrict__ bet,
    const float* __restrict__ mu, const float* __restrict__ var,
    float* __restrict__ out) {
  int blk = blockIdx.x;   // b*12+ke
  int t = threadIdx.x;
  __shared__ float zS[D2_ * E_];       // 600
  __shared__ float Rs[RNUM_ * D2_];    // 4850
  for (int i = t; i < D2_ * E_; i += 256) {
    int r = i / E_;
    float z = zbuf[(size_t)blk * (D2_ * E_) + i];
    zS[i] = (z - mu[r]) * rsqrtf(var[r] + 1e-5f) * gam[r] + bet[r];
  }
  for (int i = t; i < RNUM_ * D2_; i += 256) Rs[i] = Rm[i];
  __syncthreads();
  for (int o = t; o < E_ * RNUM_; o += 256) {
    int je = o / RNUM_;
    int k = o % RNUM_;
    float s = 0.f;
    #pragma unroll
    for (int r = 0; r < D2_; ++r) s += zS[r * E_ + je] * Rs[k * D2_ + r];
    out[(size_t)blk * (E_ * RNUM_) + o] = s;
  }
}

extern "C" void kernel_launch(void* const* d_in, const int* in_sizes, int n_in,
                              void* d_out, int out_size, void* d_ws, size_t ws_size,
                              hipStream_t stream) {
  const float* enc  = (const float*)d_in[0];
  const int*  etype = (const int*)d_in[1];
  const int*  eidv  = (const int*)d_in[2];
  const int*  midv  = (const int*)d_in[3];
  const float* tbl  = (const float*)d_in[4];
  const float* temb = (const float*)d_in[5];
  const float* iemb = (const float*)d_in[6];
  const float* W    = (const float*)d_in[7];
  const float* Rm   = (const float*)d_in[8];
  const float* gam  = (const float*)d_in[9];
  const float* bet  = (const float*)d_in[10];
  const float* mu   = (const float*)d_in[11];
  const float* var  = (const float*)d_in[12];

  // ws layout: zbuf | eswz | Abf | x
  float* ws   = (float*)d_ws;
  float* zbuf = ws;                                           // 115,200 f
  short* eswz = (short*)(zbuf + (size_t)MROWS_ * D2_ * E_);   // 159,744 sh
  short* Abf  = eswz + (size_t)104 * MROWS_ * 8;              // 7,756,800 sh
  float* x    = (float*)(Abf + (size_t)MROWS_ * NCOL_);       // 478,336 f
  float* out  = (float*)d_out;

  hipLaunchKernelGGL(k_mention_pool, dim3(B_ * NODES_), dim3(256), 0, stream,
                     enc, etype, eidv, midv, temb, iemb, x);
  hipLaunchKernelGGL(k_entity_pool, dim3(MROWS_), dim3(256), 0, stream,
                     x, tbl, eswz);
  hipLaunchKernelGGL(k_gemm, dim3((NCOL_ + 63) / 64), dim3(256), 0, stream,
                     W, eswz, Abf);
  hipLaunchKernelGGL(k_score_z, dim3(B_ * D2_), dim3(64), 0, stream,
                     Abf, eswz, zbuf);
  hipLaunchKernelGGL(k_out, dim3(MROWS_), dim3(256), 0, stream,
                     zbuf, Rm, gam, bet, mu, var, out);
}